// Round 14
// baseline (194.498 us; speedup 1.0000x reference)
//
#include <hip/hip_runtime.h>
#include <hip/hip_bf16.h>
#include <math.h>

// Problem constants
#define Bc 2
#define Tc 2048
#define Dc 1024
#define Hc 16
#define HDc 64
// M = B*T = 4096, QKV N = 3072, K = 1024

typedef __attribute__((ext_vector_type(8))) short bf16x8;
typedef __attribute__((ext_vector_type(4))) float f32x4;
typedef __attribute__((ext_vector_type(16))) float f32x16;

__device__ __forceinline__ unsigned short f2bf(float f) {
    union { float f; unsigned int u; } v; v.f = f;
    unsigned int r = (v.u + 0x7FFFu + ((v.u >> 16) & 1u)) >> 16;   // RNE
    return (unsigned short)r;
}
// pack two fp32 -> bf16x2 dword (single v_cvt_pk_bf16_f32).
__device__ __forceinline__ unsigned pack2bf(float a, float b) {
    __hip_bfloat162 t = __float22bfloat162_rn(make_float2(a, b));
    return *(unsigned*)&t;
}

// async global->LDS, 16 B per lane. LDS dest is WAVE-UNIFORM base + lane*16.
__device__ __forceinline__ void gload_lds16(const unsigned short* g,
                                            unsigned short* l) {
    __builtin_amdgcn_global_load_lds(
        (const __attribute__((address_space(1))) unsigned int*)g,
        (__attribute__((address_space(3))) unsigned int*)l,
        16, 0, 0);
}

// exp scale: 1/sqrt(64) * log2(e). FOLDED INTO Q at QKV-epilogue time
// (Q pre-scaled by CEXP; attention computes exp2(s) directly).
#define CEXP 0.1803368801111204f

// ---------------------------------------------------------------------------
// fp32 -> bf16 conversion for x, W_qkv, W_out + RoPE cos/sin table fill.
// Grid-stride (G11): 2048 blocks x 4 iterations of float4.
// ---------------------------------------------------------------------------
__global__ __launch_bounds__(256) void convert_bf16(
    const float* __restrict__ x, const float* __restrict__ wqkv,
    const float* __restrict__ wout,
    unsigned short* __restrict__ xb, unsigned short* __restrict__ wqkvb,
    unsigned short* __restrict__ woutb, float2* __restrict__ ropeTab)
{
    const int gid = blockIdx.x * 256 + threadIdx.x;      // 0..524287
    // RoPE table: 2048 x 32 entries (cos, sin), angle = t * 10000^(-i/32)
    if (gid < Tc * 32) {
        const int t = gid >> 5, i = gid & 31;
        const float freq = exp2f((float)i * -0.4152410118609203f);
        const float ang = (float)t * freq;
        ropeTab[gid] = make_float2(cosf(ang), sinf(ang));
    }
#pragma unroll
    for (int it = 0; it < 4; it++) {
        const int i = (it * 524288 + gid) * 4;           // 8,388,608 floats
        const float* src; unsigned short* dst; int off;
        if (i < 4194304)      { src = x;    dst = xb;    off = i; }
        else if (i < 7340032) { src = wqkv; dst = wqkvb; off = i - 4194304; }
        else                  { src = wout; dst = woutb; off = i - 7340032; }
        float4 v = *(const float4*)&src[off];
        ushort4 o;
        o.x = f2bf(v.x); o.y = f2bf(v.y); o.z = f2bf(v.z); o.w = f2bf(v.w);
        *(ushort4*)&dst[off] = o;
    }
}

// ---------------------------------------------------------------------------
// bf16 MFMA GEMM:  C[M,N] = A[M,K] @ W[N,K]^T + bias[N]
// Block tile (MT*32) x (NT*32), BK=64, 256 thr = 4 waves (2x2),
// per-wave tile (MT*16) x (NT*16) frags of 16x16x32.
//   <1,2,4>: 64x128 QKV + fused RoPE epilogue (Q/K [b,h,t,d]; V^T [b,h,d,t]).
//            1536 blocks = 6/CU; Q pre-scaled by CEXP (softmax fold).
//   <0,2,2>: 64x64 out-proj (fp32 C + bias) — grid 1024 blocks = 4/CU
// NO XCD remap (R7 lesson). Staging: async global_load_lds width=16 (linear
// LDS dest), global source oct PRE-SWIZZLED so fragment reads stay
// 2-way-conflict-free.
// ---------------------------------------------------------------------------
template <int MODE, int MT, int NT>
__global__ __launch_bounds__(256) void gemm_mfma(
    const unsigned short* __restrict__ A, const unsigned short* __restrict__ W,
    const float* __restrict__ bias, float* __restrict__ C,
    unsigned short* __restrict__ Qp, unsigned short* __restrict__ Kp,
    unsigned short* __restrict__ Vtp, const float2* __restrict__ ropeTab,
    int M, int N, int K)
{
    __shared__ unsigned short Apk[MT * 32 * 64];
    __shared__ unsigned short Bpk[NT * 32 * 64];

    const int tid = threadIdx.x;
    const int lane = tid & 63;
    const int wave = tid >> 6;
    const int quad = lane >> 4;
    const int c = lane & 15;
    const int wm = wave >> 1;
    const int wn = wave & 1;
    const int m0 = blockIdx.y * (MT * 32);
    const int n0 = blockIdx.x * (NT * 32);

    f32x4 acc[MT][NT];
#pragma unroll
    for (int mt = 0; mt < MT; mt++)
#pragma unroll
        for (int nt = 0; nt < NT; nt++) acc[mt][nt] = (f32x4){0.f, 0.f, 0.f, 0.f};

    // staging: wave-load of 1 KB covers 8 rows x 8 octs. lane -> (row, oct):
    // row_in_chunk = lane>>3, lds oct = lane&7 (fixed by HW linear layout).
    // source oct = (lane&7) ^ (r&7); r&7 == lane>>3 for all 8-aligned chunks.
    const int lrow = lane >> 3;
    const int srcoct = (lane & 7) ^ lrow;

    for (int k0 = 0; k0 < K; k0 += 64) {
        __syncthreads();                       // prior tile's ds_reads done
#pragma unroll
        for (int i = 0; i < MT; i++) {
            const int r = wave * (MT * 8) + i * 8 + lrow;
            gload_lds16(&A[(size_t)(m0 + r) * K + k0 + srcoct * 8],
                        &Apk[(wave * MT * 8 + i * 8) * 64]);
        }
#pragma unroll
        for (int i = 0; i < NT; i++) {
            const int r = wave * (NT * 8) + i * 8 + lrow;
            gload_lds16(&W[(size_t)(n0 + r) * K + k0 + srcoct * 8],
                        &Bpk[(wave * NT * 8 + i * 8) * 64]);
        }
        __syncthreads();                       // drains vmcnt(0): tile ready
#pragma unroll
        for (int ko = 0; ko < 2; ko++) {
            bf16x8 af[MT], bf[NT];
#pragma unroll
            for (int mt = 0; mt < MT; mt++) {
                const int m = wm * (MT * 16) + mt * 16 + c;
                af[mt] = *(const bf16x8*)&Apk[(m * 8 + ((ko * 4 + quad) ^ (m & 7))) * 8];
            }
#pragma unroll
            for (int nt = 0; nt < NT; nt++) {
                const int n = wn * (NT * 16) + nt * 16 + c;
                bf[nt] = *(const bf16x8*)&Bpk[(n * 8 + ((ko * 4 + quad) ^ (n & 7))) * 8];
            }
#pragma unroll
            for (int mt = 0; mt < MT; mt++)
#pragma unroll
                for (int nt = 0; nt < NT; nt++)
                    acc[mt][nt] = __builtin_amdgcn_mfma_f32_16x16x32_bf16(
                        af[mt], bf[nt], acc[mt][nt], 0, 0, 0);
        }
    }

    if (MODE == 0) {
#pragma unroll
        for (int mt = 0; mt < MT; mt++) {
            const int m = m0 + wm * (MT * 16) + mt * 16 + quad * 4;
#pragma unroll
            for (int nt = 0; nt < NT; nt++) {
                const int n = n0 + wn * (NT * 16) + nt * 16 + c;
                const float bv = bias[n];
#pragma unroll
                for (int reg = 0; reg < 4; reg++)
                    C[(size_t)(m + reg) * N + n] = acc[mt][nt][reg] + bv;
            }
        }
    } else {
        // MODE 1 requires NT==4 (wave covers one full 64-wide head: wn*64).
        const int n_wave = n0 + wn * 64;          // 64-aligned -> one head/wave
        const int which = n_wave >> 10;           // 0=q,1=k,2=v (block-uniform)
        const int h = (n_wave >> 6) & 15;
        const int b = m0 >> 11;
        const int t_base = (m0 & 2047) + wm * (MT * 16);   // wave's MT*16 t-rows

        __syncthreads();   // all MFMA LDS reads done; reuse Apk/Bpk as staging
        // per-wave staging region: MT*16 rows x 64 cols = MT*1024 ushorts.
        // waves {0,1} in Apk (MT*2048 us), {2,3} in Bpk.
        unsigned short* stg = ((wave < 2) ? Apk : Bpk) + (wave & 1) * (MT * 1024);

        if (which < 2) {
            // ---- Q/K with fused RoPE: rotate -> LDS tile -> coalesced store
            // Q (which==0) is additionally scaled by CEXP (softmax fold).
            unsigned short* dst = (which == 0) ? Qp : Kp;
            const float sc = (which == 0) ? CEXP : 1.0f;
#pragma unroll
            for (int mt = 0; mt < MT; mt++) {
#pragma unroll
                for (int nt = 0; nt < 2; nt++) {
                    const int i1 = nt * 16 + c;            // rotary index 0..31
                    const float bv1 = bias[n_wave + i1];
                    const float bv2 = bias[n_wave + 32 + i1];
#pragma unroll
                    for (int reg = 0; reg < 4; reg++) {
                        const int row = mt * 16 + quad * 4 + reg;   // 0..MT*16-1
                        const float2 cs = ropeTab[(t_base + row) * 32 + i1];
                        const float x1 = acc[mt][nt][reg] + bv1;
                        const float x2 = acc[mt][nt + 2][reg] + bv2;
                        const int col2 = 32 + i1;
                        stg[(row * 8 + ((i1 >> 3) ^ (row & 7))) * 8 + (i1 & 7)] =
                            f2bf((x1 * cs.x - x2 * cs.y) * sc);
                        stg[(row * 8 + ((col2 >> 3) ^ (row & 7))) * 8 + (col2 & 7)] =
                            f2bf((x1 * cs.y + x2 * cs.x) * sc);
                    }
                }
            }
            // tile [t_base..t_base+MT*16-1][0..63] is contiguous in Q/K
            const size_t obase = ((size_t)(b * Hc + h) * Tc + t_base) * HDc;
            const int oct = lane & 7;
#pragma unroll
            for (int k = 0; k < MT * 2; k++) {
                const int f = lane * 8 + k * 512;       // flat ushort offset
                const int row = f >> 6;
                bf16x8 vv = *(const bf16x8*)&stg[(row * 8 + (oct ^ (row & 7))) * 8];
                *(bf16x8*)&dst[obase + f] = vv;         // 64 lanes x 16 B = 1 KB
            }
        } else {
            // ---- V: stage transposed tile [d][t] (t-span = MT*16 = VO octs)
            constexpr int VO = MT * 2;                  // octs per d-row
#pragma unroll
            for (int mt = 0; mt < MT; mt++) {
#pragma unroll
                for (int nt = 0; nt < 4; nt++) {
                    const int d = nt * 16 + c;
                    const float bv = bias[n_wave + d];
#pragma unroll
                    for (int reg = 0; reg < 4; reg++) {
                        const int r = mt * 16 + quad * 4 + reg;   // t within tile
                        stg[(d * VO + ((r >> 3) ^ (d & (VO - 1)))) * 8 + (r & 7)] =
                            f2bf(acc[mt][nt][reg] + bv);
                    }
                }
            }
            const size_t vbase = (size_t)(b * Hc + h) * HDc * Tc;
            const int oct = lane & (VO - 1);            // t-chunk
#pragma unroll
            for (int k = 0; k < VO; k++) {
                const int d = (lane / VO) + k * (64 / VO);
                bf16x8 vv = *(const bf16x8*)&stg[(d * VO + (oct ^ (d & (VO - 1)))) * 8];
                // VO lanes cover one d-row segment (MT*16 t = VO*16 B)
                *(bf16x8*)&Vtp[vbase + (size_t)d * Tc + t_base + oct * 8] = vv;
            }
        }
    }
}

// ---------------------------------------------------------------------------
// Fused attention. R13: LDS shrunk 33792 -> 32768 B (exactly 32 KB) so FIVE
// blocks fit per CU (was 4; (256,4) A/B proved occupancy is the biggest
// lever here). Causal path byte-identical; only the global-query path's
// merge is restructured as a 2-stage tree (peak scratch 6368 floats).
// Grid = 1056 blocks:
//   blk 0..31    : global-query rows (full-T, one block per bh).
//   blk 32..1055 : causal, 2-way KEY-SPLIT (fixed-max softmax => O,l partials
//     are linear and just add); forced (256,4) occupancy x 2-phase pipeline:
//       barrier -> stage V(pair) -> QK^T+softmax (V in flight)
//       barrier -> stage K(next pair) -> PV (K in flight)
// ---------------------------------------------------------------------------
__global__ __launch_bounds__(256, 4) void attn_fused(
    const unsigned short* __restrict__ Q, const unsigned short* __restrict__ K,
    const unsigned short* __restrict__ Vt, const int* __restrict__ ids,
    unsigned short* __restrict__ AO)
{
    __shared__ __align__(16) float smem[8192];   // 32768 B -> 5 blocks/CU

    const int tid = threadIdx.x;
    const int lane = tid & 63;
    const int wave = tid >> 6;
    const int c32 = lane & 31;
    const int h = lane >> 5;
    const int blk = blockIdx.x;

    if (blk < 32) {
        // ================= global-query rows =================
        int* s_list = (int*)smem;                 // 64 ints
        int* s_cnt = (int*)smem + 64;
        float* s_m1 = smem + 128;                 // stage-1 [2][64][32]
        float* s_l1 = smem + 128 + 4096;          // [2][32]
        float* s_m2 = smem + 128 + 4160;          // stage-2 [64][32]
        float* s_l2 = s_m2 + 2048;                // [32]   (ends at 6368)

        const int bh = blk;
        const int b = bh >> 4;
        const int hd = bh & 15;
        const size_t qkbase = (size_t)bh * Tc * HDc;

        if (tid == 0) *s_cnt = 0;
        __syncthreads();
        for (int i = tid; i < Tc; i += 256) {
            int id = ids[b * Tc + i];
            if ((unsigned)(id - 2) <= 5u) {
                int p = atomicAdd(s_cnt, 1);
                if (p < 64) s_list[p] = i;
            }
        }
        __syncthreads();
        const int cnt = min(*s_cnt, 64);

        for (int pass = 0; pass * 32 < cnt; pass++) {
            const int slot = pass * 32 + c32;
            const int row = (slot < cnt) ? s_list[slot] : s_list[0];

            bf16x8 qf[4];
#pragma unroll
            for (int ko = 0; ko < 4; ko++)
                qf[ko] = *(const bf16x8*)&Q[qkbase + (size_t)row * HDc + ko * 16 + h * 8];

            f32x16 acc0 = {}, acc1 = {};
            float lacc = 0.0f;

            for (int it = wave; it < Tc / 64; it += 4) {
                const int t0 = it * 64;
                f32x16 s0 = {}, s1 = {};
#pragma unroll
                for (int ko = 0; ko < 4; ko++) {
                    const int koff = ko * 16 + h * 8;
                    bf16x8 kf0 = *(const bf16x8*)&K[qkbase + (size_t)(t0 + c32) * HDc + koff];
                    bf16x8 kf1 = *(const bf16x8*)&K[qkbase + (size_t)(t0 + 32 + c32) * HDc + koff];
                    s0 = __builtin_amdgcn_mfma_f32_32x32x16_bf16(kf0, qf[ko], s0, 0, 0, 0);
                    s1 = __builtin_amdgcn_mfma_f32_32x32x16_bf16(kf1, qf[ko], s1, 0, 0, 0);
                }
                float v[32];
#pragma unroll
                for (int r = 0; r < 16; r++) { v[r] = s0[r]; v[16 + r] = s1[r]; }
#pragma unroll
                for (int i = 0; i < 32; i++) v[i] = exp2f(v[i]);
                unsigned pk[16];
#pragma unroll
                for (int i = 0; i < 16; i++) pk[i] = pack2bf(v[2 * i], v[2 * i + 1]);
#pragma unroll
                for (int st = 1; st < 32; st <<= 1)
#pragma unroll
                    for (int i = 0; i < 32; i += 2 * st) v[i] += v[i + st];
                lacc += v[0];
#pragma unroll
                for (int ko = 0; ko < 4; ko++) {
                    const int a = (ko >> 1) * 8 + (ko & 1) * 4;
                    unsigned keep0 = h ? pk[a + 2] : pk[a + 0];
                    unsigned keep1 = h ? pk[a + 3] : pk[a + 1];
                    unsigned send0 = h ? pk[a + 0] : pk[a + 2];
                    unsigned send1 = h ? pk[a + 1] : pk[a + 3];
                    unsigned recv0 = (unsigned)__shfl_xor((int)send0, 32);
                    unsigned recv1 = (unsigned)__shfl_xor((int)send1, 32);
                    union { bf16x8 v8; unsigned u[4]; } pf;
                    pf.u[0] = h ? recv0 : keep0;
                    pf.u[1] = h ? recv1 : keep1;
                    pf.u[2] = h ? keep0 : recv0;
                    pf.u[3] = h ? keep1 : recv1;
                    const int oct = ko * 2 + h;
                    bf16x8 vf0 = *(const bf16x8*)&Vt[qkbase + (size_t)c32 * Tc + t0 + oct * 8];
                    bf16x8 vf1 = *(const bf16x8*)&Vt[qkbase + (size_t)(32 + c32) * Tc + t0 + oct * 8];
                    acc0 = __builtin_amdgcn_mfma_f32_32x32x16_bf16(vf0, pf.v8, acc0, 0, 0, 0);
                    acc1 = __builtin_amdgcn_mfma_f32_32x32x16_bf16(vf1, pf.v8, acc1, 0, 0, 0);
                }
            }

            // --- 2-stage tree merge (fits 32 KB): w2,w3 -> LDS; w0,w1 add;
            //     w1 -> LDS; w0 adds and stores from registers.
            const float lfull = lacc + __shfl_xor(lacc, 32);
            if (wave >= 2) {
#pragma unroll
                for (int r = 0; r < 16; r++) {
                    const int d = (r & 3) + 8 * (r >> 2) + 4 * h;
                    s_m1[((wave - 2) * 64 + d) * 32 + c32] = acc0[r];
                    s_m1[((wave - 2) * 64 + 32 + d) * 32 + c32] = acc1[r];
                }
                if (h == 0) s_l1[(wave - 2) * 32 + c32] = lfull;
            }
            __syncthreads();
            float lt = lfull;
            if (wave < 2) {
#pragma unroll
                for (int r = 0; r < 16; r++) {
                    const int d = (r & 3) + 8 * (r >> 2) + 4 * h;
                    acc0[r] += s_m1[(wave * 64 + d) * 32 + c32];
                    acc1[r] += s_m1[(wave * 64 + 32 + d) * 32 + c32];
                }
                lt += s_l1[wave * 32 + c32];
            }
            if (wave == 1) {
#pragma unroll
                for (int r = 0; r < 16; r++) {
                    const int d = (r & 3) + 8 * (r >> 2) + 4 * h;
                    s_m2[d * 32 + c32] = acc0[r];
                    s_m2[(32 + d) * 32 + c32] = acc1[r];
                }
                if (h == 0) s_l2[c32] = lt;
            }
            __syncthreads();
            if (wave == 0 && (pass * 32 + c32) < cnt) {
                const int qrow = s_list[pass * 32 + c32];
                const float inv = 1.0f / (lt + s_l2[c32]);
                unsigned short* dst = &AO[((size_t)(b * Tc + qrow)) * Dc + hd * HDc];
#pragma unroll
                for (int i = 0; i < 8; i++) {
                    const int r = 2 * i;
                    const int d = (r & 3) + 8 * (r >> 2) + 4 * h;   // even
                    const float a0 = acc0[r] + s_m2[d * 32 + c32];
                    const float a1 = acc0[r + 1] + s_m2[(d + 1) * 32 + c32];
                    const float b0 = acc1[r] + s_m2[(32 + d) * 32 + c32];
                    const float b1 = acc1[r + 1] + s_m2[(32 + d + 1) * 32 + c32];
                    *(unsigned*)&dst[d]      = pack2bf(a0 * inv, a1 * inv);
                    *(unsigned*)&dst[32 + d] = pack2bf(b0 * inv, b1 * inv);
                }
            }
            __syncthreads();    // next pass reuses merge regions
        }
        return;
    }

    // ====== causal path: key-split + (256,4) + 2-phase pipelined staging =====
    unsigned short* KV = (unsigned short*)smem;
    unsigned short* Ke = KV;                       // even-tile K (8 KB)
    unsigned short* Ko = KV + 4096;                // odd-tile  K
    unsigned short* Ve = KV + 8192;                // even-tile V^T
    unsigned short* Vo = KV + 12288;               // odd-tile  V^T

    const int idx = blk - 32;                      // 0..1023
    const int bh = (idx & 7) + 8 * ((idx >> 3) & 3);   // 4 bh per XCD
    const int b = bh >> 4;
    const int hd = bh & 15;
    // weight index -> j so stride-8 samples {w, w+8, w+16, w+24} (one CU's 4
    // resident blocks) give j = {u, 31-u, 8+u, 23-u}: nTiles sum == 66 const.
    const int w = idx >> 5;                        // 0..31
    const int u = w & 7, tq = w >> 3;
    const int j = (tq == 0) ? u : (tq == 1) ? 31 - u : (tq == 2) ? 8 + u : 23 - u;
    const int qb0 = j * 64;
    const int nT = j + 1;                          // 64-key tiles in [0, qb0+64)
    const int grp = wave >> 1;                     // 0: even tiles, 1: odd
    const int wq0 = qb0 + (wave & 1) * 32;         // wave's 32 q rows
    const size_t qkbase = (size_t)bh * Tc * HDc;
    const int q = wq0 + c32;

    // Q B-fragments (whole kernel): B[k=hd=ko*16+h*8+j][n=q=c32]
    bf16x8 qf[4];
#pragma unroll
    for (int ko = 0; ko < 4; ko++)
        qf[ko] = *(const bf16x8*)&Q[qkbase + (size_t)q * HDc + ko * 16 + h * 8];

    const int myid = ids[b * Tc + q];
    const bool gr = ((unsigned)(myid - 2) <= 5u);  // global row: store suppressed

    f32x16 acc0 = {}, acc1 = {};
    float lacc = 0.0f;

    // staging constants (global_load_lds: linear LDS, pre-swizzled source)
    const int lrow = lane >> 3;                    // 0..7
    const int srcoct = (lane & 7) ^ lrow;          // source oct for this lane
    const int jb = wave * 2;                       // wave's 1-KB chunk base

    auto stageK = [&](int t0, unsigned short* buf) {
#pragma unroll
        for (int i = 0; i < 2; i++) {
            const int jj = jb + i;                 // 0..7 (8 x 1 KB = 8 KB)
            const int row = jj * 8 + lrow;         // key row 0..63
            gload_lds16(&K[qkbase + (size_t)(t0 + row) * HDc + srcoct * 8],
                        &buf[jj * 512]);
        }
    };
    auto stageV = [&](int t0, unsigned short* buf) {
#pragma unroll
        for (int i = 0; i < 2; i++) {
            const int jj = jb + i;
            const int d = jj * 8 + lrow;           // d row 0..63
            gload_lds16(&Vt[qkbase + (size_t)d * Tc + t0 + srcoct * 8],
                        &buf[jj * 512]);
        }
    };

    unsigned pk[16];

    auto qkPhase = [&](int t0, const unsigned short* Kb) {
        // --- scores S^T[key][q]: 2 key-tiles of 32, contraction 64 = 4 MFMAs
        f32x16 s0 = {}, s1 = {};
#pragma unroll
        for (int ko = 0; ko < 4; ko++) {
            const int oct = ko * 2 + h;
            const int k0i = c32;
            const int k1i = 32 + c32;
            bf16x8 kf0 = *(const bf16x8*)&Kb[(k0i * 8 + (oct ^ (k0i & 7))) * 8];
            bf16x8 kf1 = *(const bf16x8*)&Kb[(k1i * 8 + (oct ^ (k1i & 7))) * 8];
            s0 = __builtin_amdgcn_mfma_f32_32x32x16_bf16(kf0, qf[ko], s0, 0, 0, 0);
            s1 = __builtin_amdgcn_mfma_f32_32x32x16_bf16(kf1, qf[ko], s1, 0, 0, 0);
        }

        // --- fixed-max softmax: p = exp2(s) (Q pre-scaled), no cross-lane
        float v[32];
#pragma unroll
        for (int r = 0; r < 16; r++) { v[r] = s0[r]; v[16 + r] = s1[r]; }
#pragma unroll
        for (int i = 0; i < 32; i++) v[i] = exp2f(v[i]);

        const bool needMask = (t0 + 63 > wq0);     // wave-uniform (diag tile)
        if (needMask) {
            const int thr = wq0 + c32 - t0 - 4 * h;
#pragma unroll
            for (int kt = 0; kt < 2; kt++)
#pragma unroll
                for (int r = 0; r < 16; r++) {
                    const int ckr = kt * 32 + (r & 3) + 8 * (r >> 2);
                    v[kt * 16 + r] = (ckr <= thr) ? v[kt * 16 + r] : 0.0f;
                }
        }

#pragma unroll
        for (int i = 0; i < 16; i++) pk[i] = pack2bf(v[2 * i], v[2 * i + 1]);

        // l accumulation: depth-5 pairwise tree, no cross-lane op
#pragma unroll
        for (int st = 1; st < 32; st <<= 1)
#pragma unroll
            for (int i = 0; i < 32; i += 2 * st) v[i] += v[i + st];
        lacc += v[0];
    };

    auto pvPhase = [&](const unsigned short* Vb) {
        // --- PV: O^T += V^T x P^T
#pragma unroll
        for (int ko = 0; ko < 4; ko++) {
            const int a = (ko >> 1) * 8 + (ko & 1) * 4;
            unsigned keep0 = h ? pk[a + 2] : pk[a + 0];
            unsigned keep1 = h ? pk[a + 3] : pk[a + 1];
            unsigned send0 = h ? pk[a + 0] : pk[a + 2];
            unsigned send1 = h ? pk[a + 1] : pk[a + 3];
            unsigned recv0 = (unsigned)__shfl_xor((int)send0, 32);
            unsigned recv1 = (unsigned)__shfl_xor((int)send1, 32);
            union { bf16x8 v8; unsigned u[4]; } pf;
            pf.u[0] = h ? recv0 : keep0;
            pf.u[1] = h ? recv1 : keep1;
            pf.u[2] = h ? keep0 : recv0;
            pf.u[3] = h ? keep1 : recv1;
            const int oct = ko * 2 + h;
            const int d0 = c32, d1 = 32 + c32;
            bf16x8 vf0 = *(const bf16x8*)&Vb[(d0 * 8 + (oct ^ (d0 & 7))) * 8];
            bf16x8 vf1 = *(const bf16x8*)&Vb[(d1 * 8 + (oct ^ (d1 & 7))) * 8];
            acc0 = __builtin_amdgcn_mfma_f32_32x32x16_bf16(vf0, pf.v8, acc0, 0, 0, 0);
            acc1 = __builtin_amdgcn_mfma_f32_32x32x16_bf16(vf1, pf.v8, acc1, 0, 0, 0);
        }
    };

    // 2-phase pipelined K-loop over tile pairs (2 barriers/pair):
    //   prologue stages K(0),K(1); per pair: V flies under QK, next K under PV.
    {
        const int t1 = (1 < nT) ? 1 : 0;
        stageK(0, Ke);
        stageK(t1 * 64, Ko);
    }
    for (int tp = 0; tp < nT; tp += 2) {
        __syncthreads();                  // K(tp),K(tp+1) ready; prior V reads done
        const int to = (tp + 1 < nT) ? tp + 1 : tp;
        stageV(tp * 64, Ve);              // V flies under QK+softmax
        stageV(to * 64, Vo);
        const bool valid = (grp == 0) || (tp + 1 < nT);
        if (valid) qkPhase(grp ? (tp + 1) * 64 : tp * 64, grp ? Ko : Ke);
        __syncthreads();                  // V ready; all K reads done
        if (tp + 2 < nT) {
            const int t3 = (tp + 3 < nT) ? tp + 3 : tp + 2;
            stageK((tp + 2) * 64, Ke);    // next K flies under PV
            stageK(t3 * 64, Ko);
        }
        if (valid) pvPhase(grp ? Vo : Ve);
    }

    // --- merge key-split partials: wave 2->0, 3->1 via LDS ([r][lane]: no
    // bank conflicts), then h-halves of l, then store.
    __syncthreads();
    float* mrg = smem + (wave & 1) * 2176;         // 2 pairs x 2176 f32
    if (wave >= 2) {
#pragma unroll
        for (int r = 0; r < 16; r++) {
            mrg[r * 64 + lane] = acc0[r];
            mrg[(16 + r) * 64 + lane] = acc1[r];
        }
        mrg[2048 + lane] = lacc;
    }
    __syncthreads();
    if (wave >= 2) return;
#pragma unroll
    for (int r = 0; r < 16; r++) {
        acc0[r] += mrg[r * 64 + lane];
        acc1[r] += mrg[(16 + r) * 64 + lane];
    }
    lacc += mrg[2048 + lane];

    const float l = lacc + __shfl_xor(lacc, 32);
    if (!gr) {
        const float inv = 1.0f / l;
        unsigned short* dst = &AO[((size_t)(b * Tc + q)) * Dc + hd * HDc];
#pragma unroll
        for (int i = 0; i < 8; i++) {
            const int r = 2 * i;
            const int d = (r & 3) + 8 * (r >> 2) + 4 * h;
            *(unsigned*)&dst[d]      = pack2bf(acc0[r] * inv, acc0[r + 1] * inv);
            *(unsigned*)&dst[32 + d] = pack2bf(acc1[r] * inv, acc1[r + 1] * inv);
        }
    }
}

// ---------------------------------------------------------------------------
extern "C" void kernel_launch(void* const* d_in, const int* in_sizes, int n_in,
                              void* d_out, int out_size, void* d_ws, size_t ws_size,
                              hipStream_t stream)
{
    const float* x    = (const float*)d_in[0];
    const int*   ids  = (const int*)d_in[1];
    const float* Wqkv = (const float*)d_in[2];
    const float* bqkv = (const float*)d_in[3];
    const float* Wout = (const float*)d_in[4];
    const float* bout = (const float*)d_in[5];
    float* out = (float*)d_out;

    const size_t TEN = (size_t)Bc * Hc * Tc * HDc;   // 4,194,304 elements
    unsigned short* xb    = (unsigned short*)d_ws;            // 4.2M us
    unsigned short* wqkvb = xb + 4194304;                     // 3.1M us
    unsigned short* woutb = wqkvb + 3145728;                  // 1.0M us
    float2* ropeTab       = (float2*)(woutb + 1048576);       // 64K float2
    unsigned short* Qb    = (unsigned short*)(ropeTab + 65536);
    unsigned short* Kb    = Qb + TEN;
    unsigned short* Vtb   = Kb + TEN;
    unsigned short* AOb   = Vtb + TEN;                        // ~51 MB total

    // 0. fp32 -> bf16 conversions + RoPE table (grid-stride x4)
    convert_bf16<<<2048, 256, 0, stream>>>(x, Wqkv, Wout, xb, wqkvb, woutb,
                                           ropeTab);
    // 1. QKV projection (MFMA) + fused RoPE -> bf16 Q/K [b,h,t,d], V^T [b,h,d,t]
    //    64x128 tiles -> 1536 blocks = 6/CU; Q pre-scaled by CEXP.
    dim3 g1(3072 / 128, 4096 / 64);
    gemm_mfma<1, 2, 4><<<g1, 256, 0, stream>>>(xb, wqkvb, bqkv, nullptr,
                                               Qb, Kb, Vtb, ropeTab,
                                               4096, 3072, 1024);
    // 2. attention (key-split causal, pipelined + (256,4), 32 KB LDS) -> AO
    attn_fused<<<1056, 256, 0, stream>>>(Qb, Kb, Vtb, ids, AOb);
    // 3. output projection (MFMA, fp32 out) — 64x64 tiles, 1024 blocks = 4/CU
    dim3 g4(1024 / 64, 4096 / 64);
    gemm_mfma<0, 2, 2><<<g4, 256, 0, stream>>>(AOb, woutb, bout, out,
                                               nullptr, nullptr, nullptr, nullptr,
                                               4096, 1024, 1024);
}

// Round 15
// 181.305 us; speedup vs baseline: 1.0728x; 1.0728x over previous
//
#include <hip/hip_runtime.h>
#include <math.h>

// Problem constants
#define Bc 2
#define Tc 2048
#define Dc 1024
#define Hc 16
#define HDc 64
// M = B*T = 4096, QKV N = 3072, K = 1024

typedef __attribute__((ext_vector_type(8))) short bf16x8;
typedef __attribute__((ext_vector_type(4))) float f32x4;
typedef __attribute__((ext_vector_type(16))) float f32x16;

__device__ __forceinline__ unsigned short f2bf(float f) {
    union { float f; unsigned int u; } v; v.f = f;
    unsigned int r = (v.u + 0x7FFFu + ((v.u >> 16) & 1u)) >> 16;   // RNE
    return (unsigned short)r;
}
// pack two fp32 -> bf16x2 dword (round-nearest, ties up): 3 VALU
__device__ __forceinline__ unsigned pack2bf(float a, float b) {
    unsigned au = __float_as_uint(a) + 0x8000u;
    unsigned bu = __float_as_uint(b) + 0x8000u;
    return __builtin_amdgcn_perm(bu, au, 0x07060302u);
}

// async global->LDS, 16 B per lane. LDS dest is WAVE-UNIFORM base + lane*16.
__device__ __forceinline__ void gload_lds16(const unsigned short* g,
                                            unsigned short* l) {
    __builtin_amdgcn_global_load_lds(
        (const __attribute__((address_space(1))) unsigned int*)g,
        (__attribute__((address_space(3))) unsigned int*)l,
        16, 0, 0);
}

// exp scale: 1/sqrt(64) * log2(e)  (fixed-max softmax: p = exp2(s*CEXP))
#define CEXP 0.1803368801111204f

// ---------------------------------------------------------------------------
// fp32 -> bf16 conversion for x, W_qkv, W_out + RoPE cos/sin table fill.
// Grid-stride (G11): 2048 blocks x 4 iterations of float4.
// ---------------------------------------------------------------------------
__global__ __launch_bounds__(256) void convert_bf16(
    const float* __restrict__ x, const float* __restrict__ wqkv,
    const float* __restrict__ wout,
    unsigned short* __restrict__ xb, unsigned short* __restrict__ wqkvb,
    unsigned short* __restrict__ woutb, float2* __restrict__ ropeTab)
{
    const int gid = blockIdx.x * 256 + threadIdx.x;      // 0..524287
    // RoPE table: 2048 x 32 entries (cos, sin), angle = t * 10000^(-i/32)
    if (gid < Tc * 32) {
        const int t = gid >> 5, i = gid & 31;
        const float freq = exp2f((float)i * -0.4152410118609203f);
        const float ang = (float)t * freq;
        ropeTab[gid] = make_float2(cosf(ang), sinf(ang));
    }
#pragma unroll
    for (int it = 0; it < 4; it++) {
        const int i = (it * 524288 + gid) * 4;           // 8,388,608 floats
        const float* src; unsigned short* dst; int off;
        if (i < 4194304)      { src = x;    dst = xb;    off = i; }
        else if (i < 7340032) { src = wqkv; dst = wqkvb; off = i - 4194304; }
        else                  { src = wout; dst = woutb; off = i - 7340032; }
        float4 v = *(const float4*)&src[off];
        ushort4 o;
        o.x = f2bf(v.x); o.y = f2bf(v.y); o.z = f2bf(v.z); o.w = f2bf(v.w);
        *(ushort4*)&dst[off] = o;
    }
}

// ---------------------------------------------------------------------------
// bf16 MFMA GEMM:  C[M,N] = A[M,K] @ W[N,K]^T + bias[N]
// Block tile (MT*32) x (NT*32), BK=64, 256 thr = 4 waves (2x2),
// per-wave tile (MT*16) x (NT*16) frags of 16x16x32.
//   <1,2,4>: 64x128 QKV + fused RoPE epilogue (Q/K [b,h,t,d]; V^T [b,h,d,t]).
//            1536 blocks = 6/CU (128x128 was 768 = 3/CU, latency-bound).
//   <0,2,2>: 64x64 out-proj (fp32 C + bias) — grid 1024 blocks = 4/CU
// NO XCD remap (R7 lesson): flat%8 band remap raised QKV 50->66us.
// Staging: async global_load_lds width=16 (linear LDS dest), global source
// oct PRE-SWIZZLED so LDS[r][o] = G[r][o ^ (r&7)] -> fragment reads stay
// 2-way-conflict-free.
// ---------------------------------------------------------------------------
template <int MODE, int MT, int NT>
__global__ __launch_bounds__(256) void gemm_mfma(
    const unsigned short* __restrict__ A, const unsigned short* __restrict__ W,
    const float* __restrict__ bias, float* __restrict__ C,
    unsigned short* __restrict__ Qp, unsigned short* __restrict__ Kp,
    unsigned short* __restrict__ Vtp, const float2* __restrict__ ropeTab,
    int M, int N, int K)
{
    __shared__ unsigned short Apk[MT * 32 * 64];
    __shared__ unsigned short Bpk[NT * 32 * 64];

    const int tid = threadIdx.x;
    const int lane = tid & 63;
    const int wave = tid >> 6;
    const int quad = lane >> 4;
    const int c = lane & 15;
    const int wm = wave >> 1;
    const int wn = wave & 1;
    const int m0 = blockIdx.y * (MT * 32);
    const int n0 = blockIdx.x * (NT * 32);

    f32x4 acc[MT][NT];
#pragma unroll
    for (int mt = 0; mt < MT; mt++)
#pragma unroll
        for (int nt = 0; nt < NT; nt++) acc[mt][nt] = (f32x4){0.f, 0.f, 0.f, 0.f};

    // staging: wave-load of 1 KB covers 8 rows x 8 octs. lane -> (row, oct):
    // row_in_chunk = lane>>3, lds oct = lane&7 (fixed by HW linear layout).
    // source oct = (lane&7) ^ (r&7); r&7 == lane>>3 for all 8-aligned chunks.
    const int lrow = lane >> 3;
    const int srcoct = (lane & 7) ^ lrow;

    for (int k0 = 0; k0 < K; k0 += 64) {
        __syncthreads();                       // prior tile's ds_reads done
#pragma unroll
        for (int i = 0; i < MT; i++) {
            const int r = wave * (MT * 8) + i * 8 + lrow;
            gload_lds16(&A[(size_t)(m0 + r) * K + k0 + srcoct * 8],
                        &Apk[(wave * MT * 8 + i * 8) * 64]);
        }
#pragma unroll
        for (int i = 0; i < NT; i++) {
            const int r = wave * (NT * 8) + i * 8 + lrow;
            gload_lds16(&W[(size_t)(n0 + r) * K + k0 + srcoct * 8],
                        &Bpk[(wave * NT * 8 + i * 8) * 64]);
        }
        __syncthreads();                       // drains vmcnt(0): tile ready
#pragma unroll
        for (int ko = 0; ko < 2; ko++) {
            bf16x8 af[MT], bf[NT];
#pragma unroll
            for (int mt = 0; mt < MT; mt++) {
                const int m = wm * (MT * 16) + mt * 16 + c;
                af[mt] = *(const bf16x8*)&Apk[(m * 8 + ((ko * 4 + quad) ^ (m & 7))) * 8];
            }
#pragma unroll
            for (int nt = 0; nt < NT; nt++) {
                const int n = wn * (NT * 16) + nt * 16 + c;
                bf[nt] = *(const bf16x8*)&Bpk[(n * 8 + ((ko * 4 + quad) ^ (n & 7))) * 8];
            }
#pragma unroll
            for (int mt = 0; mt < MT; mt++)
#pragma unroll
                for (int nt = 0; nt < NT; nt++)
                    acc[mt][nt] = __builtin_amdgcn_mfma_f32_16x16x32_bf16(
                        af[mt], bf[nt], acc[mt][nt], 0, 0, 0);
        }
    }

    if (MODE == 0) {
#pragma unroll
        for (int mt = 0; mt < MT; mt++) {
            const int m = m0 + wm * (MT * 16) + mt * 16 + quad * 4;
#pragma unroll
            for (int nt = 0; nt < NT; nt++) {
                const int n = n0 + wn * (NT * 16) + nt * 16 + c;
                const float bv = bias[n];
#pragma unroll
                for (int reg = 0; reg < 4; reg++)
                    C[(size_t)(m + reg) * N + n] = acc[mt][nt][reg] + bv;
            }
        }
    } else {
        // MODE 1 requires NT==4 (wave covers one full 64-wide head: wn*64).
        const int n_wave = n0 + wn * 64;          // 64-aligned -> one head/wave
        const int which = n_wave >> 10;           // 0=q,1=k,2=v (block-uniform)
        const int h = (n_wave >> 6) & 15;
        const int b = m0 >> 11;
        const int t_base = (m0 & 2047) + wm * (MT * 16);   // wave's MT*16 t-rows

        __syncthreads();   // all MFMA LDS reads done; reuse Apk/Bpk as staging
        // per-wave staging region: MT*16 rows x 64 cols = MT*1024 ushorts.
        // waves {0,1} in Apk (MT*2048 us), {2,3} in Bpk.
        unsigned short* stg = ((wave < 2) ? Apk : Bpk) + (wave & 1) * (MT * 1024);

        if (which < 2) {
            // ---- Q/K with fused RoPE: rotate -> LDS tile -> coalesced store
            unsigned short* dst = (which == 0) ? Qp : Kp;
#pragma unroll
            for (int mt = 0; mt < MT; mt++) {
#pragma unroll
                for (int nt = 0; nt < 2; nt++) {
                    const int i1 = nt * 16 + c;            // rotary index 0..31
                    const float bv1 = bias[n_wave + i1];
                    const float bv2 = bias[n_wave + 32 + i1];
#pragma unroll
                    for (int reg = 0; reg < 4; reg++) {
                        const int row = mt * 16 + quad * 4 + reg;   // 0..MT*16-1
                        const float2 cs = ropeTab[(t_base + row) * 32 + i1];
                        const float x1 = acc[mt][nt][reg] + bv1;
                        const float x2 = acc[mt][nt + 2][reg] + bv2;
                        const int col2 = 32 + i1;
                        stg[(row * 8 + ((i1 >> 3) ^ (row & 7))) * 8 + (i1 & 7)] =
                            f2bf(x1 * cs.x - x2 * cs.y);
                        stg[(row * 8 + ((col2 >> 3) ^ (row & 7))) * 8 + (col2 & 7)] =
                            f2bf(x1 * cs.y + x2 * cs.x);
                    }
                }
            }
            // tile [t_base..t_base+MT*16-1][0..63] is contiguous in Q/K
            const size_t obase = ((size_t)(b * Hc + h) * Tc + t_base) * HDc;
            const int oct = lane & 7;
#pragma unroll
            for (int k = 0; k < MT * 2; k++) {
                const int f = lane * 8 + k * 512;       // flat ushort offset
                const int row = f >> 6;
                bf16x8 vv = *(const bf16x8*)&stg[(row * 8 + (oct ^ (row & 7))) * 8];
                *(bf16x8*)&dst[obase + f] = vv;         // 64 lanes x 16 B = 1 KB
            }
        } else {
            // ---- V: stage transposed tile [d][t] (t-span = MT*16 = VO octs)
            constexpr int VO = MT * 2;                  // octs per d-row
#pragma unroll
            for (int mt = 0; mt < MT; mt++) {
#pragma unroll
                for (int nt = 0; nt < 4; nt++) {
                    const int d = nt * 16 + c;
                    const float bv = bias[n_wave + d];
#pragma unroll
                    for (int reg = 0; reg < 4; reg++) {
                        const int r = mt * 16 + quad * 4 + reg;   // t within tile
                        stg[(d * VO + ((r >> 3) ^ (d & (VO - 1)))) * 8 + (r & 7)] =
                            f2bf(acc[mt][nt][reg] + bv);
                    }
                }
            }
            const size_t vbase = (size_t)(b * Hc + h) * HDc * Tc;
            const int oct = lane & (VO - 1);            // t-chunk
#pragma unroll
            for (int k = 0; k < VO; k++) {
                const int d = (lane / VO) + k * (64 / VO);
                bf16x8 vv = *(const bf16x8*)&stg[(d * VO + (oct ^ (d & (VO - 1)))) * 8];
                // VO lanes cover one d-row segment (MT*16 t = VO*16 B)
                *(bf16x8*)&Vtp[vbase + (size_t)d * Tc + t_base + oct * 8] = vv;
            }
        }
    }
}

// ---------------------------------------------------------------------------
// Fused attention — best-measured configuration (R11: 183.8us total, attn
// ~50us). R13/R14 A/B proved LDS-residency (32KB, 5 blocks/CU) is NOT the
// limiter (occupancy unchanged, dur +2us) — this 33792-B / (256,4) / 2-phase
// pipelined key-split structure is the measured floor of the explored space.
// Grid = 1056 blocks:
//   blk 0..31    : global-query rows (full-T, one block per bh).
//   blk 32..1055 : causal, 2-way KEY-SPLIT (fixed-max softmax => O,l partials
//     are linear and just add); forced (256,4) occupancy x 2-phase pipeline:
//       barrier -> stage V(pair) -> QK^T+softmax (V in flight)
//       barrier -> stage K(next pair) -> PV (K in flight)
// ---------------------------------------------------------------------------
__global__ __launch_bounds__(256, 4) void attn_fused(
    const unsigned short* __restrict__ Q, const unsigned short* __restrict__ K,
    const unsigned short* __restrict__ Vt, const int* __restrict__ ids,
    unsigned short* __restrict__ AO)
{
    __shared__ __align__(16) float smem[8448];   // 33792 B, overlaid per path

    const int tid = threadIdx.x;
    const int lane = tid & 63;
    const int wave = tid >> 6;
    const int c32 = lane & 31;
    const int h = lane >> 5;
    const int blk = blockIdx.x;

    if (blk < 32) {
        // ================= global-query rows =================
        int* s_list = (int*)smem;                 // 64
        int* s_cnt = (int*)smem + 64;
        float* s_accm = smem + 128;               // [4][64][32]
        float* s_lm = s_accm + 8192;              // [4][32]

        const int bh = blk;
        const int b = bh >> 4;
        const int hd = bh & 15;
        const size_t qkbase = (size_t)bh * Tc * HDc;

        if (tid == 0) *s_cnt = 0;
        __syncthreads();
        for (int i = tid; i < Tc; i += 256) {
            int id = ids[b * Tc + i];
            if ((unsigned)(id - 2) <= 5u) {
                int p = atomicAdd(s_cnt, 1);
                if (p < 64) s_list[p] = i;
            }
        }
        __syncthreads();
        const int cnt = min(*s_cnt, 64);

        for (int pass = 0; pass * 32 < cnt; pass++) {
            const int slot = pass * 32 + c32;
            const int row = (slot < cnt) ? s_list[slot] : s_list[0];

            bf16x8 qf[4];
#pragma unroll
            for (int ko = 0; ko < 4; ko++)
                qf[ko] = *(const bf16x8*)&Q[qkbase + (size_t)row * HDc + ko * 16 + h * 8];

            f32x16 acc0 = {}, acc1 = {};
            float lacc = 0.0f;

            for (int it = wave; it < Tc / 64; it += 4) {
                const int t0 = it * 64;
                f32x16 s0 = {}, s1 = {};
#pragma unroll
                for (int ko = 0; ko < 4; ko++) {
                    const int koff = ko * 16 + h * 8;
                    bf16x8 kf0 = *(const bf16x8*)&K[qkbase + (size_t)(t0 + c32) * HDc + koff];
                    bf16x8 kf1 = *(const bf16x8*)&K[qkbase + (size_t)(t0 + 32 + c32) * HDc + koff];
                    s0 = __builtin_amdgcn_mfma_f32_32x32x16_bf16(kf0, qf[ko], s0, 0, 0, 0);
                    s1 = __builtin_amdgcn_mfma_f32_32x32x16_bf16(kf1, qf[ko], s1, 0, 0, 0);
                }
                float v[32];
#pragma unroll
                for (int r = 0; r < 16; r++) { v[r] = s0[r]; v[16 + r] = s1[r]; }
#pragma unroll
                for (int i = 0; i < 32; i++) v[i] = exp2f(v[i] * CEXP);
                unsigned pk[16];
#pragma unroll
                for (int i = 0; i < 16; i++) pk[i] = pack2bf(v[2 * i], v[2 * i + 1]);
#pragma unroll
                for (int st = 1; st < 32; st <<= 1)
#pragma unroll
                    for (int i = 0; i < 32; i += 2 * st) v[i] += v[i + st];
                lacc += v[0];
#pragma unroll
                for (int ko = 0; ko < 4; ko++) {
                    const int a = (ko >> 1) * 8 + (ko & 1) * 4;
                    unsigned keep0 = h ? pk[a + 2] : pk[a + 0];
                    unsigned keep1 = h ? pk[a + 3] : pk[a + 1];
                    unsigned send0 = h ? pk[a + 0] : pk[a + 2];
                    unsigned send1 = h ? pk[a + 1] : pk[a + 3];
                    unsigned recv0 = (unsigned)__shfl_xor((int)send0, 32);
                    unsigned recv1 = (unsigned)__shfl_xor((int)send1, 32);
                    union { bf16x8 v8; unsigned u[4]; } pf;
                    pf.u[0] = h ? recv0 : keep0;
                    pf.u[1] = h ? recv1 : keep1;
                    pf.u[2] = h ? keep0 : recv0;
                    pf.u[3] = h ? keep1 : recv1;
                    const int oct = ko * 2 + h;
                    bf16x8 vf0 = *(const bf16x8*)&Vt[qkbase + (size_t)c32 * Tc + t0 + oct * 8];
                    bf16x8 vf1 = *(const bf16x8*)&Vt[qkbase + (size_t)(32 + c32) * Tc + t0 + oct * 8];
                    acc0 = __builtin_amdgcn_mfma_f32_32x32x16_bf16(vf0, pf.v8, acc0, 0, 0, 0);
                    acc1 = __builtin_amdgcn_mfma_f32_32x32x16_bf16(vf1, pf.v8, acc1, 0, 0, 0);
                }
            }

            const float lfull = lacc + __shfl_xor(lacc, 32);
            if (h == 0) s_lm[wave * 32 + c32] = lfull;
#pragma unroll
            for (int r = 0; r < 16; r++) {
                const int d = (r & 3) + 8 * (r >> 2) + 4 * h;
                s_accm[(wave * 64 + d) * 32 + c32] = acc0[r];
                s_accm[(wave * 64 + 32 + d) * 32 + c32] = acc1[r];
            }
            __syncthreads();
            for (int i = tid; i < 2048; i += 256) {
                const int sl = i >> 6, d = i & 63;
                if (pass * 32 + sl < cnt) {
                    const float o = s_accm[(0 * 64 + d) * 32 + sl] + s_accm[(1 * 64 + d) * 32 + sl] +
                                    s_accm[(2 * 64 + d) * 32 + sl] + s_accm[(3 * 64 + d) * 32 + sl];
                    const float lt = s_lm[sl] + s_lm[32 + sl] + s_lm[64 + sl] + s_lm[96 + sl];
                    const int qrow = s_list[pass * 32 + sl];
                    AO[((size_t)(b * Tc + qrow)) * Dc + hd * HDc + d] = f2bf(o / lt);
                }
            }
            __syncthreads();
        }
        return;
    }

    // ====== causal path: key-split + (256,4) + 2-phase pipelined staging =====
    unsigned short* KV = (unsigned short*)smem;
    unsigned short* Ke = KV;                       // even-tile K (8 KB)
    unsigned short* Ko = KV + 4096;                // odd-tile  K
    unsigned short* Ve = KV + 8192;                // even-tile V^T
    unsigned short* Vo = KV + 12288;               // odd-tile  V^T

    const int idx = blk - 32;                      // 0..1023
    const int bh = (idx & 7) + 8 * ((idx >> 3) & 3);   // 4 bh per XCD
    const int b = bh >> 4;
    const int hd = bh & 15;
    // weight index -> j so stride-8 samples {w, w+8, w+16, w+24} (one CU's 4
    // resident blocks) give j = {u, 31-u, 8+u, 23-u}: nTiles sum == 66 const.
    const int w = idx >> 5;                        // 0..31
    const int u = w & 7, tq = w >> 3;
    const int j = (tq == 0) ? u : (tq == 1) ? 31 - u : (tq == 2) ? 8 + u : 23 - u;
    const int qb0 = j * 64;
    const int nT = j + 1;                          // 64-key tiles in [0, qb0+64)
    const int grp = wave >> 1;                     // 0: even tiles, 1: odd
    const int wq0 = qb0 + (wave & 1) * 32;         // wave's 32 q rows
    const size_t qkbase = (size_t)bh * Tc * HDc;
    const int q = wq0 + c32;

    // Q B-fragments (whole kernel): B[k=hd=ko*16+h*8+j][n=q=c32]
    bf16x8 qf[4];
#pragma unroll
    for (int ko = 0; ko < 4; ko++)
        qf[ko] = *(const bf16x8*)&Q[qkbase + (size_t)q * HDc + ko * 16 + h * 8];

    const int myid = ids[b * Tc + q];
    const bool gr = ((unsigned)(myid - 2) <= 5u);  // global row: store suppressed

    f32x16 acc0 = {}, acc1 = {};
    float lacc = 0.0f;

    // staging constants (global_load_lds: linear LDS, pre-swizzled source)
    const int lrow = lane >> 3;                    // 0..7
    const int srcoct = (lane & 7) ^ lrow;          // source oct for this lane
    const int jb = wave * 2;                       // wave's 1-KB chunk base

    auto stageK = [&](int t0, unsigned short* buf) {
#pragma unroll
        for (int i = 0; i < 2; i++) {
            const int jj = jb + i;                 // 0..7 (8 x 1 KB = 8 KB)
            const int row = jj * 8 + lrow;         // key row 0..63
            gload_lds16(&K[qkbase + (size_t)(t0 + row) * HDc + srcoct * 8],
                        &buf[jj * 512]);
        }
    };
    auto stageV = [&](int t0, unsigned short* buf) {
#pragma unroll
        for (int i = 0; i < 2; i++) {
            const int jj = jb + i;
            const int d = jj * 8 + lrow;           // d row 0..63
            gload_lds16(&Vt[qkbase + (size_t)d * Tc + t0 + srcoct * 8],
                        &buf[jj * 512]);
        }
    };

    unsigned pk[16];

    auto qkPhase = [&](int t0, const unsigned short* Kb) {
        // --- scores S^T[key][q]: 2 key-tiles of 32, contraction 64 = 4 MFMAs
        f32x16 s0 = {}, s1 = {};
#pragma unroll
        for (int ko = 0; ko < 4; ko++) {
            const int oct = ko * 2 + h;
            const int k0i = c32;
            const int k1i = 32 + c32;
            bf16x8 kf0 = *(const bf16x8*)&Kb[(k0i * 8 + (oct ^ (k0i & 7))) * 8];
            bf16x8 kf1 = *(const bf16x8*)&Kb[(k1i * 8 + (oct ^ (k1i & 7))) * 8];
            s0 = __builtin_amdgcn_mfma_f32_32x32x16_bf16(kf0, qf[ko], s0, 0, 0, 0);
            s1 = __builtin_amdgcn_mfma_f32_32x32x16_bf16(kf1, qf[ko], s1, 0, 0, 0);
        }

        // --- fixed-max softmax: p = exp2(s*CEXP), no chains, no cross-lane
        float v[32];
#pragma unroll
        for (int r = 0; r < 16; r++) { v[r] = s0[r]; v[16 + r] = s1[r]; }
#pragma unroll
        for (int i = 0; i < 32; i++) v[i] = exp2f(v[i] * CEXP);

        const bool needMask = (t0 + 63 > wq0);     // wave-uniform (diag tile)
        if (needMask) {
            const int thr = wq0 + c32 - t0 - 4 * h;
#pragma unroll
            for (int kt = 0; kt < 2; kt++)
#pragma unroll
                for (int r = 0; r < 16; r++) {
                    const int ckr = kt * 32 + (r & 3) + 8 * (r >> 2);
                    v[kt * 16 + r] = (ckr <= thr) ? v[kt * 16 + r] : 0.0f;
                }
        }

#pragma unroll
        for (int i = 0; i < 16; i++) pk[i] = pack2bf(v[2 * i], v[2 * i + 1]);

        // l accumulation: depth-5 pairwise tree, no cross-lane op
#pragma unroll
        for (int st = 1; st < 32; st <<= 1)
#pragma unroll
            for (int i = 0; i < 32; i += 2 * st) v[i] += v[i + st];
        lacc += v[0];
    };

    auto pvPhase = [&](const unsigned short* Vb) {
        // --- PV: O^T += V^T x P^T
#pragma unroll
        for (int ko = 0; ko < 4; ko++) {
            const int a = (ko >> 1) * 8 + (ko & 1) * 4;
            unsigned keep0 = h ? pk[a + 2] : pk[a + 0];
            unsigned keep1 = h ? pk[a + 3] : pk[a + 1];
            unsigned send0 = h ? pk[a + 0] : pk[a + 2];
            unsigned send1 = h ? pk[a + 1] : pk[a + 3];
            unsigned recv0 = (unsigned)__shfl_xor((int)send0, 32);
            unsigned recv1 = (unsigned)__shfl_xor((int)send1, 32);
            union { bf16x8 v8; unsigned u[4]; } pf;
            pf.u[0] = h ? recv0 : keep0;
            pf.u[1] = h ? recv1 : keep1;
            pf.u[2] = h ? keep0 : recv0;
            pf.u[3] = h ? keep1 : recv1;
            const int oct = ko * 2 + h;
            const int d0 = c32, d1 = 32 + c32;
            bf16x8 vf0 = *(const bf16x8*)&Vb[(d0 * 8 + (oct ^ (d0 & 7))) * 8];
            bf16x8 vf1 = *(const bf16x8*)&Vb[(d1 * 8 + (oct ^ (d1 & 7))) * 8];
            acc0 = __builtin_amdgcn_mfma_f32_32x32x16_bf16(vf0, pf.v8, acc0, 0, 0, 0);
            acc1 = __builtin_amdgcn_mfma_f32_32x32x16_bf16(vf1, pf.v8, acc1, 0, 0, 0);
        }
    };

    // 2-phase pipelined K-loop over tile pairs (2 barriers/pair):
    //   prologue stages K(0),K(1); per pair: V flies under QK, next K under PV.
    {
        const int t1 = (1 < nT) ? 1 : 0;
        stageK(0, Ke);
        stageK(t1 * 64, Ko);
    }
    for (int tp = 0; tp < nT; tp += 2) {
        __syncthreads();                  // K(tp),K(tp+1) ready; prior V reads done
        const int to = (tp + 1 < nT) ? tp + 1 : tp;
        stageV(tp * 64, Ve);              // V flies under QK+softmax
        stageV(to * 64, Vo);
        const bool valid = (grp == 0) || (tp + 1 < nT);
        if (valid) qkPhase(grp ? (tp + 1) * 64 : tp * 64, grp ? Ko : Ke);
        __syncthreads();                  // V ready; all K reads done
        if (tp + 2 < nT) {
            const int t3 = (tp + 3 < nT) ? tp + 3 : tp + 2;
            stageK((tp + 2) * 64, Ke);    // next K flies under PV
            stageK(t3 * 64, Ko);
        }
        if (valid) pvPhase(grp ? Vo : Ve);
    }

    // --- merge key-split partials: wave 2->0, 3->1 via LDS ([r][lane]: no
    // bank conflicts), then h-halves of l, then store.
    __syncthreads();
    float* mrg = smem + (wave & 1) * 2176;         // 2 pairs x 2176 f32
    if (wave >= 2) {
#pragma unroll
        for (int r = 0; r < 16; r++) {
            mrg[r * 64 + lane] = acc0[r];
            mrg[(16 + r) * 64 + lane] = acc1[r];
        }
        mrg[2048 + lane] = lacc;
    }
    __syncthreads();
    if (wave >= 2) return;
#pragma unroll
    for (int r = 0; r < 16; r++) {
        acc0[r] += mrg[r * 64 + lane];
        acc1[r] += mrg[(16 + r) * 64 + lane];
    }
    lacc += mrg[2048 + lane];

    const float l = lacc + __shfl_xor(lacc, 32);
    if (!gr) {
        const float inv = 1.0f / l;
        unsigned short* dst = &AO[((size_t)(b * Tc + q)) * Dc + hd * HDc];
#pragma unroll
        for (int i = 0; i < 8; i++) {
            const int r = 2 * i;
            const int d = (r & 3) + 8 * (r >> 2) + 4 * h;
            *(unsigned*)&dst[d]      = pack2bf(acc0[r] * inv, acc0[r + 1] * inv);
            *(unsigned*)&dst[32 + d] = pack2bf(acc1[r] * inv, acc1[r + 1] * inv);
        }
    }
}

// ---------------------------------------------------------------------------
extern "C" void kernel_launch(void* const* d_in, const int* in_sizes, int n_in,
                              void* d_out, int out_size, void* d_ws, size_t ws_size,
                              hipStream_t stream)
{
    const float* x    = (const float*)d_in[0];
    const int*   ids  = (const int*)d_in[1];
    const float* Wqkv = (const float*)d_in[2];
    const float* bqkv = (const float*)d_in[3];
    const float* Wout = (const float*)d_in[4];
    const float* bout = (const float*)d_in[5];
    float* out = (float*)d_out;

    const size_t TEN = (size_t)Bc * Hc * Tc * HDc;   // 4,194,304 elements
    unsigned short* xb    = (unsigned short*)d_ws;            // 4.2M us
    unsigned short* wqkvb = xb + 4194304;                     // 3.1M us
    unsigned short* woutb = wqkvb + 3145728;                  // 1.0M us
    float2* ropeTab       = (float2*)(woutb + 1048576);       // 64K float2
    unsigned short* Qb    = (unsigned short*)(ropeTab + 65536);
    unsigned short* Kb    = Qb + TEN;
    unsigned short* Vtb   = Kb + TEN;
    unsigned short* AOb   = Vtb + TEN;                        // ~51 MB total

    // 0. fp32 -> bf16 conversions + RoPE table (grid-stride x4)
    convert_bf16<<<2048, 256, 0, stream>>>(x, Wqkv, Wout, xb, wqkvb, woutb,
                                           ropeTab);
    // 1. QKV projection (MFMA) + fused RoPE -> bf16 Q/K [b,h,t,d], V^T [b,h,d,t]
    //    64x128 tiles -> 1536 blocks = 6/CU (was 768 = 3/CU at 128x128)
    dim3 g1(3072 / 128, 4096 / 64);
    gemm_mfma<1, 2, 4><<<g1, 256, 0, stream>>>(xb, wqkvb, bqkv, nullptr,
                                               Qb, Kb, Vtb, ropeTab,
                                               4096, 3072, 1024);
    // 2. attention (key-split causal, pipelined + (256,4)) -> bf16 AO
    attn_fused<<<1056, 256, 0, stream>>>(Qb, Kb, Vtb, ids, AOb);
    // 3. output projection (MFMA, fp32 out) — 64x64 tiles, 1024 blocks = 4/CU
    dim3 g4(1024 / 64, 4096 / 64);
    gemm_mfma<0, 2, 2><<<g4, 256, 0, stream>>>(AOb, woutb, bout, out,
                                               nullptr, nullptr, nullptr, nullptr,
                                               4096, 1024, 1024);
}